// Round 5
// baseline (980.930 us; speedup 1.0000x reference)
//
#include <hip/hip_runtime.h>
#include <hip/hip_bf16.h>

#define NB   8
#define NS   5
#define NQ   128
#define TT   16
#define DD   2048
#define NROW 1024               // B*nq
#define NSROW (NB * NS * TT)    // 640 supp rows
#define PF   4                  // prefetch depth (k-steps)
#define LAMI 10.0f
#define LAMF 0.1f

typedef __attribute__((ext_vector_type(8))) short  short8;
typedef __attribute__((ext_vector_type(4))) float  float4v;

// pack two f32 -> bf16x2 (RNE)
static __device__ __forceinline__ unsigned int f2bf2(float x, float y) {
    union { float f; unsigned int u; } a, b; a.f = x; b.f = y;
    unsigned int ra = a.u + 0x7fffu + ((a.u >> 16) & 1u);
    unsigned int rb = b.u + 0x7fffu + ((b.u >> 16) & 1u);
    return (ra >> 16) | (rb & 0xffff0000u);
}

static __device__ __forceinline__ float lse2f(float x, float y) {
    float mx = fmaxf(x, y), mn = fminf(x, y);
    return mx + __logf(1.0f + __expf(mn - mx));
}

// supp only: f32 -> bf16 + row sum-of-squares. One wave per row (640 rows).
__global__ __launch_bounds__(256) void
preproc_supp(const float* __restrict__ supp, unsigned short* __restrict__ suppBf,
             float* __restrict__ suppSq)
{
    const int wave = threadIdx.x >> 6, lane = threadIdx.x & 63;
    const int row = blockIdx.x * 4 + wave;           // 0..639
    const float* src = supp + (size_t)row * DD;
    unsigned short* dst = suppBf + (size_t)row * DD;
    float ss = 0.f;
    #pragma unroll
    for (int i = 0; i < 8; ++i) {
        float4 v = *reinterpret_cast<const float4*>(src + i * 256 + lane * 4);
        uint2 pv = { f2bf2(v.x, v.y), f2bf2(v.z, v.w) };
        *reinterpret_cast<uint2*>(dst + i * 256 + lane * 4) = pv;
        ss += v.x * v.x + v.y * v.y + v.z * v.z + v.w * v.w;
    }
    #pragma unroll
    for (int off = 32; off >= 1; off >>= 1) ss += __shfl_xor(ss, off, 64);
    if (lane == 0) suppSq[row] = ss;
}

// One block per (b,q); 5 waves, wave = support s. B-fragments loaded DIRECTLY from
// f32 query in global (per-lane layout == MFMA B-operand layout), converted to bf16
// in registers; A direct from L2-resident suppBf. No LDS tile, no K-loop syncthreads;
// depth-PF register prefetch keeps ~12 loads/lane in flight. Fused DTW at the end.
__global__ __launch_bounds__(320, 5) void
dist_dtw_kernel(const unsigned short* __restrict__ suppBf, const float* __restrict__ suppSq,
                const float* __restrict__ query,
                float* __restrict__ out_tam, float* __restrict__ t1w, float* __restrict__ t2w)
{
    __shared__ float ssq[96];
    __shared__ float distS[NS][TT][TT];
    __shared__ float tamv[16];

    const int tid  = threadIdx.x;
    const int blk  = blockIdx.x;          // b*128 + q
    const int wave = tid >> 6;            // 0..4 == s
    const int lane = tid & 63;
    const int fr   = lane & 15;
    const int quad = lane >> 4;

    if (tid < 80) ssq[tid] = suppSq[(blk >> 7) * (NS * TT) + tid];

    const unsigned short* ap =
        suppBf + ((size_t)((blk >> 7) * NS + wave) * TT + fr) * DD + quad * 8;
    const float* qp = query + ((size_t)(blk * TT + fr)) * DD + quad * 8;

    float4 qbuf[PF][2];
    short8 abuf[PF];
    #pragma unroll
    for (int i = 0; i < PF; ++i) {
        qbuf[i][0] = *reinterpret_cast<const float4*>(qp + i * 32);
        qbuf[i][1] = *reinterpret_cast<const float4*>(qp + i * 32 + 4);
        abuf[i]    = *reinterpret_cast<const short8*>(ap + i * 32);
    }

    float4v acc = {0.f, 0.f, 0.f, 0.f};
    float qss = 0.f;

    #pragma unroll
    for (int k = 0; k < 64; ++k) {
        const int sl = k % PF;
        float4 v0 = qbuf[sl][0], v1 = qbuf[sl][1];
        short8 a  = abuf[sl];
        if (k + PF < 64) {
            qbuf[sl][0] = *reinterpret_cast<const float4*>(qp + (k + PF) * 32);
            qbuf[sl][1] = *reinterpret_cast<const float4*>(qp + (k + PF) * 32 + 4);
            abuf[sl]    = *reinterpret_cast<const short8*>(ap + (k + PF) * 32);
        }
        union { short8 s8; unsigned int u[4]; } bu;
        bu.u[0] = f2bf2(v0.x, v0.y);
        bu.u[1] = f2bf2(v0.z, v0.w);
        bu.u[2] = f2bf2(v1.x, v1.y);
        bu.u[3] = f2bf2(v1.z, v1.w);
        qss += v0.x * v0.x + v0.y * v0.y + v0.z * v0.z + v0.w * v0.w
             + v1.x * v1.x + v1.y * v1.y + v1.z * v1.z + v1.w * v1.w;
        acc = __builtin_amdgcn_mfma_f32_16x16x32_bf16(a, bu.s8, acc, 0, 0, 0);
        if ((k & 15) == 15 && k < 63)
            __builtin_amdgcn_s_barrier();   // loose wave alignment (no waitcnt drain)
    }

    // query row sumsq: lane holds partial for row fr; reduce across quads
    qss += __shfl_xor(qss, 16, 64);
    qss += __shfl_xor(qss, 32, 64);
    if (wave == 0 && lane < 16) ssq[80 + lane] = qss;
    __syncthreads();

    // epilogue: dist[s][l][m] = 1 - dot / max(||s_l||*||q_m||, eps)
    {
        float qn = sqrtf(ssq[80 + fr]);
        #pragma unroll
        for (int r = 0; r < 4; ++r) {
            int l = quad * 4 + r;
            float denom = fmaxf(sqrtf(ssq[wave * 16 + l]) * qn, 1e-8f);
            distS[wave][l][fr] = 1.0f - acc[r] / denom;
        }
    }
    __syncthreads();

    // DTW: anti-diagonal wavefront; wave s, lanes 0..17 dir=0, 32..49 dir=1
    if ((lane & 31) <= 17) {
        const int g   = lane & 31;
        const int dir = lane >> 5;
        const int s   = wave;
        float val = 0.f, vprev = 0.f;
        #pragma unroll
        for (int t = 1; t <= 32; ++t) {
            float left = __shfl_up(val,   1, 32);
            float diag = __shfl_up(vprev, 1, 32);
            int l = t - g;
            if (g >= 1 && l >= 0 && l <= 15) {
                float d = 0.f;
                if (g <= 16) d = dir ? distS[s][15 - l][16 - g] : distS[s][l][g - 1];
                float nv;
                if (l == 0) {
                    nv = left + d;
                } else if (g == 1 || g == 17) {
                    nv = -LAMF * lse2f(lse2f(-diag * LAMI, -left * LAMI), -val * LAMI) + d;
                } else {
                    float lo2 = fminf(diag, left), hi2 = fmaxf(diag, left);
                    nv = lo2 - LAMF * __logf(1.0f + __expf((lo2 - hi2) * LAMI)) + d;
                }
                vprev = val; val = nv;
            }
        }
        if (g == 17) tamv[s * 2 + dir] = val;
    }
    __syncthreads();

    if (tid < NS) {
        float t1 = tamv[2 * tid], t2 = tamv[2 * tid + 1];
        int n = blk * NS + tid;
        t1w[n] = t1;
        t2w[n] = t2;
        out_tam[n] = 0.5f * (t1 + t2);
    }
}

__global__ __launch_bounds__(1024) void
loss_kernel(const float* __restrict__ t1w, const float* __restrict__ t2w,
            const int* __restrict__ ys, float* __restrict__ out)
{
    __shared__ float red[16];
    const int row = threadIdx.x;

    float t1[NS], t2[NS];
    #pragma unroll
    for (int s = 0; s < NS; ++s) { t1[s] = t1w[row * NS + s]; t2[s] = t2w[row * NS + s]; }
    const int y = ys[row];

    float mx1 = -t1[0], mx2 = -t2[0];
    #pragma unroll
    for (int s = 1; s < NS; ++s) { mx1 = fmaxf(mx1, -t1[s]); mx2 = fmaxf(mx2, -t2[s]); }
    float s1 = 0.f, s2 = 0.f;
    #pragma unroll
    for (int s = 0; s < NS; ++s) { s1 += __expf(-t1[s] - mx1); s2 += __expf(-t2[s] - mx2); }
    float lse1  = mx1 + __logf(s1);
    float lse2v = mx2 + __logf(s2);

    float ty1 = t1[0], ty2 = t2[0];
    #pragma unroll
    for (int s = 1; s < NS; ++s) { if (y == s) { ty1 = t1[s]; ty2 = t2[s]; } }

    float c = 0.5f * ((lse1 + ty1) + (lse2v + ty2));

    #pragma unroll
    for (int off = 32; off >= 1; off >>= 1) c += __shfl_down(c, off, 64);
    if ((row & 63) == 0) red[row >> 6] = c;
    __syncthreads();
    if (row == 0) {
        float tot = 0.f;
        #pragma unroll
        for (int i = 0; i < 16; ++i) tot += red[i];
        out[0] = tot * (1.0f / (float)NROW);
    }
}

extern "C" void kernel_launch(void* const* d_in, const int* in_sizes, int n_in,
                              void* d_out, int out_size, void* d_ws, size_t ws_size,
                              hipStream_t stream) {
    const float* supp  = (const float*)d_in[0];
    const float* query = (const float*)d_in[1];
    const int*   ys    = (const int*)d_in[2];
    float* out = (float*)d_out;

    float* t1w    = (float*)d_ws;                              // 5120 f32
    float* t2w    = t1w + NROW * NS;                           // 5120 f32
    float* suppSq = t2w + NROW * NS;                           // 640 f32
    unsigned short* suppBf = (unsigned short*)(suppSq + NSROW);// 640*2048 bf16

    preproc_supp<<<NSROW / 4, 256, 0, stream>>>(supp, suppBf, suppSq);
    dist_dtw_kernel<<<NROW, 320, 0, stream>>>(suppBf, suppSq, query, out + 1, t1w, t2w);
    loss_kernel<<<1, 1024, 0, stream>>>(t1w, t2w, ys, out);
}

// Round 6
// 270.557 us; speedup vs baseline: 3.6256x; 3.6256x over previous
//
#include <hip/hip_runtime.h>
#include <hip/hip_bf16.h>

#define NB   8
#define NS   5
#define NQ   128
#define TT   16
#define DD   2048
#define NROW 1024               // B*nq
#define NSROW (NB * NS * TT)    // 640 supp rows
#define NSTEP 64                // K steps of 32
#define SPW  13                 // k-steps per wave (last wave: 12)
#define LAMI 10.0f
#define LAMF 0.1f

typedef __attribute__((ext_vector_type(8))) short  short8;
typedef __attribute__((ext_vector_type(4))) float  float4v;

// pack two f32 -> bf16x2 (RNE)
static __device__ __forceinline__ unsigned int f2bf2(float x, float y) {
    union { float f; unsigned int u; } a, b; a.f = x; b.f = y;
    unsigned int ra = a.u + 0x7fffu + ((a.u >> 16) & 1u);
    unsigned int rb = b.u + 0x7fffu + ((b.u >> 16) & 1u);
    return (ra >> 16) | (rb & 0xffff0000u);
}

static __device__ __forceinline__ float lse2f(float x, float y) {
    float mx = fmaxf(x, y), mn = fminf(x, y);
    return mx + __logf(1.0f + __expf(mn - mx));
}

// supp only: f32 -> bf16 + row sum-of-squares. One wave per row (640 rows).
__global__ __launch_bounds__(256) void
preproc_supp(const float* __restrict__ supp, unsigned short* __restrict__ suppBf,
             float* __restrict__ suppSq)
{
    const int wave = threadIdx.x >> 6, lane = threadIdx.x & 63;
    const int row = blockIdx.x * 4 + wave;           // 0..639
    const float* src = supp + (size_t)row * DD;
    unsigned short* dst = suppBf + (size_t)row * DD;
    float ss = 0.f;
    #pragma unroll
    for (int i = 0; i < 8; ++i) {
        float4 v = *reinterpret_cast<const float4*>(src + i * 256 + lane * 4);
        uint2 pv = { f2bf2(v.x, v.y), f2bf2(v.z, v.w) };
        *reinterpret_cast<uint2*>(dst + i * 256 + lane * 4) = pv;
        ss += v.x * v.x + v.y * v.y + v.z * v.z + v.w * v.w;
    }
    #pragma unroll
    for (int off = 32; off >= 1; off >>= 1) ss += __shfl_xor(ss, off, 64);
    if (lane == 0) suppSq[row] = ss;
}

// One block per (b,q); 5 waves. Wave w owns K-slice [w*13*32 ..), computing ALL 5
// supports for its slice: query loaded from global exactly once per block (B-frag
// reused in-register across the 5 MFMAs), A from L2-hot suppBf. No K-loop barriers,
// no LDS B-tile. Partials reduced via LDS, then fused epilogue + wavefront DTW.
__global__ __launch_bounds__(320, 4) void
dist_dtw_kernel(const unsigned short* __restrict__ suppBf, const float* __restrict__ suppSq,
                const float* __restrict__ query,
                float* __restrict__ out_tam, float* __restrict__ t1w, float* __restrict__ t2w)
{
    __shared__ float sP[NS][NS][TT][17];   // [slice][supp][l][m] (+1 pad)
    __shared__ float ssqS[80];
    __shared__ float ssqQp[NS][16];
    __shared__ float ssqQ[16];
    __shared__ float distS[NS][TT][TT];
    __shared__ float tamv[16];

    const int tid  = threadIdx.x;
    const int blk  = blockIdx.x;          // b*128 + q
    const int wave = tid >> 6;            // 0..4 = K-slice
    const int lane = tid & 63;
    const int fr   = lane & 15;
    const int quad = lane >> 4;

    if (tid < 80) ssqS[tid] = suppSq[(blk >> 7) * (NS * TT) + tid];

    const float* qp = query + ((size_t)(blk * TT + fr)) * DD + quad * 8;
    const unsigned short* ap[NS];
    #pragma unroll
    for (int s = 0; s < NS; ++s)
        ap[s] = suppBf + ((size_t)((blk >> 7) * NS + s) * TT + fr) * DD + quad * 8;

    const int kbase = wave * SPW;

    float4 bb[2][2];
    short8 aa[2][NS];
    // preload step i=0 (k = kbase, always < 64)
    bb[0][0] = *reinterpret_cast<const float4*>(qp + kbase * 32);
    bb[0][1] = *reinterpret_cast<const float4*>(qp + kbase * 32 + 4);
    #pragma unroll
    for (int s = 0; s < NS; ++s)
        aa[0][s] = *reinterpret_cast<const short8*>(ap[s] + kbase * 32);

    float4v acc[NS];
    #pragma unroll
    for (int s = 0; s < NS; ++s) acc[s] = (float4v){0.f, 0.f, 0.f, 0.f};
    float qss = 0.f;

    #pragma unroll
    for (int i = 0; i < SPW; ++i) {
        const int k   = kbase + i;
        const int cur = i & 1, nxt = cur ^ 1;
        if (i + 1 < SPW && k + 1 < NSTEP) {
            bb[nxt][0] = *reinterpret_cast<const float4*>(qp + (k + 1) * 32);
            bb[nxt][1] = *reinterpret_cast<const float4*>(qp + (k + 1) * 32 + 4);
            #pragma unroll
            for (int s = 0; s < NS; ++s)
                aa[nxt][s] = *reinterpret_cast<const short8*>(ap[s] + (k + 1) * 32);
        }
        if (k < NSTEP) {
            float4 v0 = bb[cur][0], v1 = bb[cur][1];
            union { short8 s8; unsigned int u[4]; } bu;
            bu.u[0] = f2bf2(v0.x, v0.y);
            bu.u[1] = f2bf2(v0.z, v0.w);
            bu.u[2] = f2bf2(v1.x, v1.y);
            bu.u[3] = f2bf2(v1.z, v1.w);
            qss += v0.x * v0.x + v0.y * v0.y + v0.z * v0.z + v0.w * v0.w
                 + v1.x * v1.x + v1.y * v1.y + v1.z * v1.z + v1.w * v1.w;
            #pragma unroll
            for (int s = 0; s < NS; ++s)
                acc[s] = __builtin_amdgcn_mfma_f32_16x16x32_bf16(aa[cur][s], bu.s8, acc[s], 0, 0, 0);
        }
    }

    // query row sumsq partial for this slice: reduce across quads (same fr)
    qss += __shfl_xor(qss, 16, 64);
    qss += __shfl_xor(qss, 32, 64);
    if (lane < 16) ssqQp[wave][lane] = qss;

    // stash partial accumulators
    #pragma unroll
    for (int s = 0; s < NS; ++s)
        #pragma unroll
        for (int r = 0; r < 4; ++r)
            sP[wave][s][quad * 4 + r][fr] = acc[s][r];
    __syncthreads();

    if (tid < 16) {
        float t = 0.f;
        #pragma unroll
        for (int w = 0; w < NS; ++w) t += ssqQp[w][tid];
        ssqQ[tid] = sqrtf(t);
    }
    __syncthreads();

    // epilogue: wave = support s. dist[s][l][m] = 1 - dot / max(||s_l||*||q_m||, eps)
    {
        const int s = wave;
        float qn = ssqQ[fr];
        #pragma unroll
        for (int r = 0; r < 4; ++r) {
            int l = quad * 4 + r;
            float dot = 0.f;
            #pragma unroll
            for (int w = 0; w < NS; ++w) dot += sP[w][s][l][fr];
            float denom = fmaxf(sqrtf(ssqS[s * 16 + l]) * qn, 1e-8f);
            distS[s][l][fr] = 1.0f - dot / denom;
        }
    }
    __syncthreads();

    // DTW: anti-diagonal wavefront; wave s, lanes 0..17 dir=0, 32..49 dir=1
    if ((lane & 31) <= 17) {
        const int g   = lane & 31;
        const int dir = lane >> 5;
        const int s   = wave;
        float val = 0.f, vprev = 0.f;
        #pragma unroll
        for (int t = 1; t <= 32; ++t) {
            float left = __shfl_up(val,   1, 32);
            float diag = __shfl_up(vprev, 1, 32);
            int l = t - g;
            if (g >= 1 && l >= 0 && l <= 15) {
                float d = 0.f;
                if (g <= 16) d = dir ? distS[s][15 - l][16 - g] : distS[s][l][g - 1];
                float nv;
                if (l == 0) {
                    nv = left + d;
                } else if (g == 1 || g == 17) {
                    nv = -LAMF * lse2f(lse2f(-diag * LAMI, -left * LAMI), -val * LAMI) + d;
                } else {
                    float lo2 = fminf(diag, left), hi2 = fmaxf(diag, left);
                    nv = lo2 - LAMF * __logf(1.0f + __expf((lo2 - hi2) * LAMI)) + d;
                }
                vprev = val; val = nv;
            }
        }
        if (g == 17) tamv[s * 2 + dir] = val;
    }
    __syncthreads();

    if (tid < NS) {
        float t1 = tamv[2 * tid], t2 = tamv[2 * tid + 1];
        int n = blk * NS + tid;
        t1w[n] = t1;
        t2w[n] = t2;
        out_tam[n] = 0.5f * (t1 + t2);
    }
}

__global__ __launch_bounds__(1024) void
loss_kernel(const float* __restrict__ t1w, const float* __restrict__ t2w,
            const int* __restrict__ ys, float* __restrict__ out)
{
    __shared__ float red[16];
    const int row = threadIdx.x;

    float t1[NS], t2[NS];
    #pragma unroll
    for (int s = 0; s < NS; ++s) { t1[s] = t1w[row * NS + s]; t2[s] = t2w[row * NS + s]; }
    const int y = ys[row];

    float mx1 = -t1[0], mx2 = -t2[0];
    #pragma unroll
    for (int s = 1; s < NS; ++s) { mx1 = fmaxf(mx1, -t1[s]); mx2 = fmaxf(mx2, -t2[s]); }
    float s1 = 0.f, s2 = 0.f;
    #pragma unroll
    for (int s = 0; s < NS; ++s) { s1 += __expf(-t1[s] - mx1); s2 += __expf(-t2[s] - mx2); }
    float lse1  = mx1 + __logf(s1);
    float lse2v = mx2 + __logf(s2);

    float ty1 = t1[0], ty2 = t2[0];
    #pragma unroll
    for (int s = 1; s < NS; ++s) { if (y == s) { ty1 = t1[s]; ty2 = t2[s]; } }

    float c = 0.5f * ((lse1 + ty1) + (lse2v + ty2));

    #pragma unroll
    for (int off = 32; off >= 1; off >>= 1) c += __shfl_down(c, off, 64);
    if ((row & 63) == 0) red[row >> 6] = c;
    __syncthreads();
    if (row == 0) {
        float tot = 0.f;
        #pragma unroll
        for (int i = 0; i < 16; ++i) tot += red[i];
        out[0] = tot * (1.0f / (float)NROW);
    }
}

extern "C" void kernel_launch(void* const* d_in, const int* in_sizes, int n_in,
                              void* d_out, int out_size, void* d_ws, size_t ws_size,
                              hipStream_t stream) {
    const float* supp  = (const float*)d_in[0];
    const float* query = (const float*)d_in[1];
    const int*   ys    = (const int*)d_in[2];
    float* out = (float*)d_out;

    float* t1w    = (float*)d_ws;                              // 5120 f32
    float* t2w    = t1w + NROW * NS;                           // 5120 f32
    float* suppSq = t2w + NROW * NS;                           // 640 f32
    unsigned short* suppBf = (unsigned short*)(suppSq + NSROW);// 640*2048 bf16

    preproc_supp<<<NSROW / 4, 256, 0, stream>>>(supp, suppBf, suppSq);
    dist_dtw_kernel<<<NROW, 320, 0, stream>>>(suppBf, suppSq, query, out + 1, t1w, t2w);
    loss_kernel<<<1, 1024, 0, stream>>>(t1w, t2w, ys, out);
}